// Round 3
// baseline (4628.494 us; speedup 1.0000x reference)
//
#include <hip/hip_runtime.h>
#include <hip/hip_bf16.h>
#include <math.h>

#define B_SEG 64
#define LMAXP 512
#define HDIM 256
#define HDIV 128
#define NHEADS 4
#define DH 32

typedef unsigned short u16;
typedef unsigned int u32;

__device__ __forceinline__ float bf2f(u16 u) {
    u32 v = ((u32)u) << 16;
    float f;
    __builtin_memcpy(&f, &v, 4);
    return f;
}

__device__ __forceinline__ u16 f2bf(float f) {
    u32 v;
    __builtin_memcpy(&v, &f, 4);
    u32 r = v + 0x7fffu + ((v >> 16) & 1u);
    return (u16)(r >> 16);
}

__device__ __forceinline__ void cvt8(const uint4 w, float* o) {
    o[0] = bf2f((u16)(w.x & 0xffff)); o[1] = bf2f((u16)(w.x >> 16));
    o[2] = bf2f((u16)(w.y & 0xffff)); o[3] = bf2f((u16)(w.y >> 16));
    o[4] = bf2f((u16)(w.z & 0xffff)); o[5] = bf2f((u16)(w.z >> 16));
    o[6] = bf2f((u16)(w.w & 0xffff)); o[7] = bf2f((u16)(w.w >> 16));
}

// ---- dtype-generic element access (F32: storage is float; else bf16) ----
template<bool F32> __device__ __forceinline__ float ld1(const void* p, size_t i) {
    if (F32) return ((const float*)p)[i];
    return bf2f(((const u16*)p)[i]);
}
template<bool F32> __device__ __forceinline__ void ld8(const void* p, size_t i, float* o) {
    if (F32) {
        const float4* q = (const float4*)((const float*)p + i);
        float4 a = q[0], b = q[1];
        o[0] = a.x; o[1] = a.y; o[2] = a.z; o[3] = a.w;
        o[4] = b.x; o[5] = b.y; o[6] = b.z; o[7] = b.w;
    } else {
        cvt8(*(const uint4*)((const u16*)p + i), o);
    }
}
template<bool F32> __device__ __forceinline__ void st1(void* p, size_t i, float v) {
    if (F32) ((float*)p)[i] = v;
    else ((u16*)p)[i] = f2bf(v);
}

// meta: [0..63] src counts, [64..127] dst counts, [128..191] src offs,
//       [192..255] dst offs, [256] = 1 if float storage is f32 else 0 (bf16)
__global__ void k_offsets(const int* __restrict__ sc_raw,
                          const int* __restrict__ dc_raw,
                          const u16* __restrict__ probe,  // rv1 raw bytes
                          int* __restrict__ meta) {
    if (threadIdx.x != 0 || blockIdx.x != 0) return;
    // counts in [256,512]; int64 storage -> int32 view has 0 at odd idx
    bool is64 = (sc_raw[1] == 0);
    int so = 0, dofs = 0;
    for (int i = 0; i < B_SEG; i++) {
        int s = is64 ? sc_raw[2 * i] : sc_raw[i];
        int d = is64 ? dc_raw[2 * i] : dc_raw[i];
        meta[i] = s;
        meta[64 + i] = d;
        meta[128 + i] = so;
        meta[192 + i] = dofs;
        so += s;
        dofs += d;
    }
    // rv1 in [0.5,1.5]: bf16 storage => every u16 high byte == 0x3F.
    // f32 storage => even u16 words are mantissa bits (random high byte).
    bool isbf = ((probe[0] >> 8) == 0x3F) && ((probe[2] >> 8) == 0x3F) &&
                ((probe[4] >> 8) == 0x3F);
    meta[256] = isbf ? 0 : 1;
}

// ---------------- projections ----------------
// One block (128 threads) per token per projection.
// blockIdx.y: 0=q(from dst_h), 1=k(from src_h), 2=v(from src_h)
// Ragged head-major: buf[off*HDIV + h*(cnt*DH) + pos*DH + d] (elements)
template<bool F32> __device__ __forceinline__ void proj_body(
    const void* src_h, const void* dst_h,
    const void* Wq, const void* bq, const void* Wk, const void* bk,
    const void* Wv, const void* bv, const int* meta,
    void* qbuf, void* kvbuf, int ntot, float* hrow) {
    int bl = blockIdx.x;
    int b = bl >> 9;
    int pos = bl & (LMAXP - 1);
    int which = blockIdx.y;
    int cnt = (which == 0) ? meta[64 + b] : meta[b];
    if (pos >= cnt) return;  // block-uniform
    int off = (which == 0) ? meta[192 + b] : meta[128 + b];
    const void* hsrc = (which == 0) ? dst_h : src_h;
    size_t hbase = (size_t)(off + pos) * HDIM;
    const void* W = (which == 0) ? Wq : ((which == 1) ? Wk : Wv);
    const void* bias = (which == 0) ? bq : ((which == 1) ? bk : bv);

    int tid = threadIdx.x;
    if (tid < 32) {
        float tmp[8];
        ld8<F32>(hsrc, hbase + (size_t)tid * 8, tmp);
#pragma unroll
        for (int j = 0; j < 8; j++) hrow[tid * 8 + j] = tmp[j];
    }
    __syncthreads();

    float acc = 0.f;
#pragma unroll
    for (int kk = 0; kk < HDIM / 8; kk++) {
        float wf[8];
        ld8<F32>(W, (size_t)tid * HDIM + kk * 8, wf);
#pragma unroll
        for (int j = 0; j < 8; j++) acc += wf[j] * hrow[kk * 8 + j];
    }
    acc += ld1<F32>(bias, tid);
    int d = tid >> 2, hh = tid & 3;  // channel c -> (d=c/4, h=c%4)
    size_t oidx = (size_t)off * HDIV + (size_t)hh * ((size_t)cnt * DH)
                + (size_t)pos * DH + d;
    if (which == 0) st1<F32>(qbuf, oidx, acc);
    else st1<F32>(kvbuf, oidx + (which == 2 ? (size_t)ntot * HDIV : 0), acc);
}

__global__ __launch_bounds__(128) void k_proj(
    const void* src_h, const void* dst_h,
    const void* Wq, const void* bq, const void* Wk, const void* bk,
    const void* Wv, const void* bv, const int* __restrict__ meta,
    void* qbuf, void* kvbuf, int ntot) {
    __shared__ float hrow[HDIM];
    if (meta[256])
        proj_body<true>(src_h, dst_h, Wq, bq, Wk, bk, Wv, bv, meta, qbuf, kvbuf, ntot, hrow);
    else
        proj_body<false>(src_h, dst_h, Wq, bq, Wk, bk, Wv, bv, meta, qbuf, kvbuf, ntot, hrow);
}

// ---------------- attention ----------------
// One block (4 waves) per (segment, dst pos); wave = head.
template<bool F32> __device__ __forceinline__ void attn_body(
    const void* qbuf, const void* kvbuf, const int* meta, void* msg,
    int ntot, float (*sc)[LMAXP]) {
    int bl = blockIdx.x;
    int b = bl >> 9;
    int pos = bl & (LMAXP - 1);
    int ndst = meta[64 + b];
    if (pos >= ndst) return;  // block-uniform
    int ns = meta[b];
    int soff = meta[128 + b];
    int doff = meta[192 + b];
    int tid = threadIdx.x;
    int h = tid >> 6;
    int lane = tid & 63;

    float qv[DH];
    size_t qbase = (size_t)doff * HDIV + (size_t)h * ((size_t)ndst * DH)
                 + (size_t)pos * DH;
#pragma unroll
    for (int i = 0; i < 4; i++) ld8<F32>(qbuf, qbase + i * 8, &qv[i * 8]);

    size_t kbase = (size_t)soff * HDIV + (size_t)h * ((size_t)ns * DH);
    float lmax = -1e30f;
    for (int m = lane; m < ns; m += 64) {
        float acc = 0.f;
#pragma unroll
        for (int i = 0; i < 4; i++) {
            float kf[8];
            ld8<F32>(kvbuf, kbase + (size_t)m * DH + i * 8, kf);
#pragma unroll
            for (int j = 0; j < 8; j++) acc += kf[j] * qv[i * 8 + j];
        }
        acc *= 0.17677669529663687f;  // 1/sqrt(32)
        sc[h][m] = acc;
        lmax = fmaxf(lmax, acc);
    }
#pragma unroll
    for (int s = 1; s < 64; s <<= 1) lmax = fmaxf(lmax, __shfl_xor(lmax, s, 64));

    float lsum = 0.f;
    for (int m = lane; m < ns; m += 64) {
        float e = __expf(sc[h][m] - lmax);
        sc[h][m] = e;
        lsum += e;
    }
#pragma unroll
    for (int s = 1; s < 64; s <<= 1) lsum += __shfl_xor(lsum, s, 64);
    float inv = 1.f / lsum;

    __syncthreads();  // sc[] visible across lanes

    int d = lane & 31, half = lane >> 5;
    size_t vbase = (size_t)ntot * HDIV + kbase + d;
    float acc = 0.f;
    for (int m = half; m < ns; m += 2)
        acc += sc[h][m] * ld1<F32>(kvbuf, vbase + (size_t)m * DH);
    acc += __shfl_xor(acc, 32, 64);
    if (lane < 32)
        st1<F32>(msg, (size_t)(doff + pos) * HDIV + d * NHEADS + h, acc * inv);
}

__global__ __launch_bounds__(256) void k_attn(
    const void* qbuf, const void* kvbuf, const int* __restrict__ meta,
    void* msg, int ntot) {
    __shared__ float sc[NHEADS][LMAXP];
    if (meta[256]) attn_body<true>(qbuf, kvbuf, meta, msg, ntot, sc);
    else attn_body<false>(qbuf, kvbuf, meta, msg, ntot, sc);
}

// ---------------- merge conv + MLP + BN + residual ----------------
template<bool F32> __device__ __forceinline__ void mlp_body(
    const void* dst_h, const void* msg,
    const void* Wm, const void* bm, const void* W1, const void* b1,
    const void* g1, const void* be1, const void* rm1, const void* rv1,
    const void* W2, const void* b2, const void* g2, const void* be2,
    const void* rm2, const void* rv2, void* out,
    float* dh, float* mrow, float* hm, float* x1) {
    int t = blockIdx.x;
    int tid = threadIdx.x;

    dh[tid] = ld1<F32>(dst_h, (size_t)t * HDIM + tid);
    if (tid < HDIV) mrow[tid] = ld1<F32>(msg, (size_t)t * HDIV + tid);
    __syncthreads();

    if (tid < HDIV) {
        float acc = 0.f;
#pragma unroll
        for (int kk = 0; kk < HDIV / 8; kk++) {
            float wf[8];
            ld8<F32>(Wm, (size_t)tid * HDIV + kk * 8, wf);
#pragma unroll
            for (int j = 0; j < 8; j++) acc += wf[j] * mrow[kk * 8 + j];
        }
        hm[tid] = acc + ld1<F32>(bm, tid);
    }
    __syncthreads();

    float acc1;
    {
        float acc = 0.f;
#pragma unroll
        for (int kk = 0; kk < HDIM / 8; kk++) {
            float wf[8];
            ld8<F32>(W1, (size_t)tid * (HDIM + HDIV) + kk * 8, wf);
#pragma unroll
            for (int j = 0; j < 8; j++) acc += wf[j] * dh[kk * 8 + j];
        }
#pragma unroll
        for (int kk = 0; kk < HDIV / 8; kk++) {
            float wf[8];
            ld8<F32>(W1, (size_t)tid * (HDIM + HDIV) + HDIM + kk * 8, wf);
#pragma unroll
            for (int j = 0; j < 8; j++) acc += wf[j] * hm[kk * 8 + j];
        }
        acc += ld1<F32>(b1, tid);
        float s = ld1<F32>(g1, tid) * rsqrtf(ld1<F32>(rv1, tid) + 1e-5f);
        acc = (acc - ld1<F32>(rm1, tid)) * s + ld1<F32>(be1, tid);
        acc1 = fmaxf(acc, 0.f);
    }
    x1[tid] = acc1;
    __syncthreads();
    {
        float acc = 0.f;
#pragma unroll
        for (int kk = 0; kk < HDIM / 8; kk++) {
            float wf[8];
            ld8<F32>(W2, (size_t)tid * HDIM + kk * 8, wf);
#pragma unroll
            for (int j = 0; j < 8; j++) acc += wf[j] * x1[kk * 8 + j];
        }
        acc += ld1<F32>(b2, tid);
        float s = ld1<F32>(g2, tid) * rsqrtf(ld1<F32>(rv2, tid) + 1e-5f);
        acc = (acc - ld1<F32>(rm2, tid)) * s + ld1<F32>(be2, tid);
        st1<F32>(out, (size_t)t * HDIM + tid, dh[tid] + acc);
    }
}

__global__ __launch_bounds__(256) void k_mlp(
    const void* dst_h, const void* msg,
    const void* Wm, const void* bm, const void* W1, const void* b1,
    const void* g1, const void* be1, const void* rm1, const void* rv1,
    const void* W2, const void* b2, const void* g2, const void* be2,
    const void* rm2, const void* rv2, const int* __restrict__ meta, void* out) {
    __shared__ float dh[HDIM];
    __shared__ float mrow[HDIV];
    __shared__ float hm[HDIV];
    __shared__ float x1[HDIM];
    if (meta[256])
        mlp_body<true>(dst_h, msg, Wm, bm, W1, b1, g1, be1, rm1, rv1,
                       W2, b2, g2, be2, rm2, rv2, out, dh, mrow, hm, x1);
    else
        mlp_body<false>(dst_h, msg, Wm, bm, W1, b1, g1, be1, rm1, rv1,
                        W2, b2, g2, be2, rm2, rv2, out, dh, mrow, hm, x1);
}

extern "C" void kernel_launch(void* const* d_in, const int* in_sizes, int n_in,
                              void* d_out, int out_size, void* d_ws, size_t ws_size,
                              hipStream_t stream) {
    const void* src_h = d_in[0];
    const void* dst_h = d_in[1];
    const int* snv = (const int*)d_in[2];
    const int* dnv = (const int*)d_in[3];
    const void* Wq = d_in[4];  const void* bq = d_in[5];
    const void* Wk = d_in[6];  const void* bk = d_in[7];
    const void* Wv = d_in[8];  const void* bv = d_in[9];
    const void* Wm = d_in[10]; const void* bm = d_in[11];
    const void* W1 = d_in[12]; const void* b1 = d_in[13];
    const void* g1 = d_in[14]; const void* be1 = d_in[15];
    const void* rm1 = d_in[16]; const void* rv1 = d_in[17];
    const void* W2 = d_in[18]; const void* b2 = d_in[19];
    const void* g2 = d_in[20]; const void* be2 = d_in[21];
    const void* rm2 = d_in[22]; const void* rv2 = d_in[23];

    int ntot = out_size / HDIM;  // 24576 packed tokens

    // ws layout sized for the f32 worst case (~25.2 MB):
    //   [0,4KB)   meta   [4KB, +ntot*HDIV*4)  q   [.., +ntot*HDIV*4)  msg
    // In bf16 mode the q/msg regions are half-used. k|v scratch = d_out
    // (exactly out_size elements in either mode), consumed by k_attn
    // before k_mlp overwrites d_out with the final result.
    char* ws = (char*)d_ws;
    int* meta = (int*)ws;
    void* qbuf = (void*)(ws + 4096);
    void* msg = (void*)(ws + 4096 + (size_t)ntot * HDIV * 4);
    void* kvbuf = d_out;

    k_offsets<<<dim3(1), dim3(64), 0, stream>>>(snv, dnv, (const u16*)rv1, meta);
    k_proj<<<dim3(B_SEG * LMAXP, 3), dim3(128), 0, stream>>>(
        src_h, dst_h, Wq, bq, Wk, bk, Wv, bv, meta, qbuf, kvbuf, ntot);
    k_attn<<<dim3(B_SEG * LMAXP), dim3(256), 0, stream>>>(qbuf, kvbuf, meta, msg, ntot);
    k_mlp<<<dim3(ntot), dim3(256), 0, stream>>>(
        dst_h, msg, Wm, bm, W1, b1, g1, be1, rm1, rv1,
        W2, b2, g2, be2, rm2, rv2, meta, d_out);
}

// Round 4
// 299.629 us; speedup vs baseline: 15.4474x; 15.4474x over previous
//
#include <hip/hip_runtime.h>
#include <hip/hip_bf16.h>
#include <math.h>

#define B_SEG 64
#define HDIM 256
#define HDIV 128
#define NHEADS 4
#define DH 32

typedef unsigned short u16;
typedef unsigned int u32;

typedef __attribute__((ext_vector_type(8))) short s8v;   // 8 x bf16 (4 VGPR)
typedef __attribute__((ext_vector_type(4))) float f4v;   // mfma accum

__device__ __forceinline__ u16 f2bf(float f) {
    u32 v;
    __builtin_memcpy(&v, &f, 4);
    u32 r = v + 0x7fffu + ((v >> 16) & 1u);
    return (u16)(r >> 16);
}

// meta: [0..63] src counts, [64..127] dst counts, [128..191] src offs, [192..255] dst offs
__global__ void k_offsets(const int* __restrict__ sc_raw,
                          const int* __restrict__ dc_raw,
                          int* __restrict__ meta) {
    if (threadIdx.x != 0 || blockIdx.x != 0) return;
    bool is64 = (sc_raw[1] == 0);  // counts in [256,512]; int64 => 0 at odd idx
    int so = 0, dofs = 0;
    for (int i = 0; i < B_SEG; i++) {
        int s = is64 ? sc_raw[2 * i] : sc_raw[i];
        int d = is64 ? dc_raw[2 * i] : dc_raw[i];
        meta[i] = s; meta[64 + i] = d;
        meta[128 + i] = so; meta[192 + i] = dofs;
        so += s; dofs += d;
    }
}

// Weight prep: f32->bf16 + head-deinterleave permutations + BN folding.
// Head permute: dest channel c' = h*32+d  <->  src channel c = d*4+h.
__global__ __launch_bounds__(256) void k_prep(
    const float* __restrict__ Wq, const float* __restrict__ bq,
    const float* __restrict__ Wk, const float* __restrict__ bk,
    const float* __restrict__ Wv, const float* __restrict__ bv,
    const float* __restrict__ Wm, const float* __restrict__ bm,
    const float* __restrict__ W1, const float* __restrict__ b1,
    const float* __restrict__ g1, const float* __restrict__ be1,
    const float* __restrict__ rm1, const float* __restrict__ rv1,
    const float* __restrict__ W2, const float* __restrict__ b2,
    const float* __restrict__ g2, const float* __restrict__ be2,
    const float* __restrict__ rm2, const float* __restrict__ rv2,
    u16* __restrict__ pWq, u16* __restrict__ pWkv, u16* __restrict__ pWm,
    u16* __restrict__ pW1, u16* __restrict__ pW2,
    float* __restrict__ bqp, float* __restrict__ bkvp, float* __restrict__ bmp,
    float* __restrict__ sc1, float* __restrict__ sh1,
    float* __restrict__ sc2, float* __restrict__ sh2) {
    int idx = blockIdx.x * 256 + threadIdx.x;
    if (idx < 32768) {                       // Wq': rows permuted
        int cp = idx >> 8, k = idx & 255;
        int c = ((cp & 31) << 2) | (cp >> 5);
        pWq[idx] = f2bf(Wq[c * 256 + k]);
    } else if (idx < 98304) {                // Wkv': k rows 0..127, v rows 128..255
        int i = idx - 32768;
        int rp = i >> 8, k = i & 255;
        int r = rp & 127;
        int c = ((r & 31) << 2) | (r >> 5);
        float v = (rp < 128) ? Wk[c * 256 + k] : Wv[c * 256 + k];
        pWkv[i] = f2bf(v);
    } else if (idx < 114688) {               // Wm': cols permuted
        int i = idx - 98304;
        int o = i >> 7, cp = i & 127;
        int c = ((cp & 31) << 2) | (cp >> 5);
        pWm[i] = f2bf(Wm[o * 128 + c]);
    } else if (idx < 212992) {               // W1 plain
        int i = idx - 114688;
        pW1[i] = f2bf(W1[i]);
    } else if (idx < 278528) {               // W2 plain
        int i = idx - 212992;
        pW2[i] = f2bf(W2[i]);
    } else if (idx < 279552) {               // params
        int p = idx - 278528;
        if (p < 128) { int c = ((p & 31) << 2) | (p >> 5); bqp[p] = bq[c]; }
        else if (p < 384) {
            int r = p - 128; int rr = r & 127;
            int c = ((rr & 31) << 2) | (rr >> 5);
            bkvp[r] = (r < 128) ? bk[c] : bv[c];
        } else if (p < 512) { bmp[p - 384] = bm[p - 384]; }
        else if (p < 768) {
            int o = p - 512; float s = g1[o] * rsqrtf(rv1[o] + 1e-5f);
            sc1[o] = s; sh1[o] = (b1[o] - rm1[o]) * s + be1[o];
        } else {
            int o = p - 768; float s = g2[o] * rsqrtf(rv2[o] + 1e-5f);
            sc2[o] = s; sh2[o] = (b2[o] - rm2[o]) * s + be2[o];
        }
    }
}

// f32 -> bf16 activation convert. y==0: src_h -> srcb[N,256].
// y==1: dst_h -> xcat[N,384] cols 0..255.
__global__ __launch_bounds__(256) void k_convert(
    const float* __restrict__ src, const float* __restrict__ dst,
    u16* __restrict__ srcb, u16* __restrict__ xcat, int ntot) {
    int i = blockIdx.x * 256 + threadIdx.x;  // 4 elems per thread
    if (i >= ntot * 64) return;
    if (blockIdx.y == 0) {
        float4 v = ((const float4*)src)[i];
        ushort4 o = {f2bf(v.x), f2bf(v.y), f2bf(v.z), f2bf(v.w)};
        ((ushort4*)srcb)[i] = o;
    } else {
        float4 v = ((const float4*)dst)[i];
        ushort4 o = {f2bf(v.x), f2bf(v.y), f2bf(v.z), f2bf(v.w)};
        int row = i >> 6, c4 = i & 63;
        *(ushort4*)(&xcat[(size_t)row * 384 + c4 * 4]) = o;
    }
}

// Generic bf16 MFMA GEMM: C[m][n] = sum_k A[m][k] * Bw[n][k], M=grid.x*128,
// N=grid.y*128. Epilogue: v = acc*scale[n]+shift[n]; relu; +resid; store.
// flags: 1=relu, 2=f32 output.
__global__ __launch_bounds__(256) void k_gemm(
    const u16* __restrict__ A, int lda,
    const u16* __restrict__ Bw, int K,
    const float* __restrict__ scale, const float* __restrict__ shift,
    const float* __restrict__ resid,
    void* __restrict__ Cout, int ldc, int coff, int flags) {
    __shared__ u16 Al[128 * 32];
    __shared__ u16 Bl[128 * 32];
    int m0 = blockIdx.x * 128, n0 = blockIdx.y * 128;
    int tid = threadIdx.x;
    int w = tid >> 6, lane = tid & 63;
    int wm = w & 1, wn = w >> 1;
    int l15 = lane & 15, quad = lane >> 4;
    f4v acc[4][4] = {};

    for (int k0 = 0; k0 < K; k0 += 32) {
#pragma unroll
        for (int c = tid; c < 512; c += 256) {  // 2 iters: 16B chunks
            int row = c >> 2, off = (c & 3) << 3;
            *(uint4*)(&Al[row * 32 + off]) =
                *(const uint4*)(&A[(size_t)(m0 + row) * lda + k0 + off]);
            *(uint4*)(&Bl[row * 32 + off]) =
                *(const uint4*)(&Bw[(size_t)(n0 + row) * K + k0 + off]);
        }
        __syncthreads();
        s8v af[4], bf[4];
#pragma unroll
        for (int i = 0; i < 4; i++)
            af[i] = *(const s8v*)(&Al[(wm * 64 + i * 16 + l15) * 32 + quad * 8]);
#pragma unroll
        for (int j = 0; j < 4; j++)
            bf[j] = *(const s8v*)(&Bl[(wn * 64 + j * 16 + l15) * 32 + quad * 8]);
#pragma unroll
        for (int i = 0; i < 4; i++)
#pragma unroll
            for (int j = 0; j < 4; j++)
                acc[i][j] = __builtin_amdgcn_mfma_f32_16x16x32_bf16(
                    af[i], bf[j], acc[i][j], 0, 0, 0);
        __syncthreads();
    }
#pragma unroll
    for (int i = 0; i < 4; i++) {
#pragma unroll
        for (int j = 0; j < 4; j++) {
            int n = n0 + wn * 64 + j * 16 + l15;
            float sc = scale ? scale[n] : 1.f;
            float sh = shift ? shift[n] : 0.f;
#pragma unroll
            for (int r = 0; r < 4; r++) {
                int m = m0 + wm * 64 + i * 16 + quad * 4 + r;
                float v = acc[i][j][r] * sc + sh;
                if (flags & 1) v = fmaxf(v, 0.f);
                if (resid) v += resid[(size_t)m * 256 + n];
                if (flags & 2) ((float*)Cout)[(size_t)m * ldc + coff + n] = v;
                else ((u16*)Cout)[(size_t)m * ldc + coff + n] = f2bf(v);
            }
        }
    }
}

// Attention: block (b, h). LDS: K[512][32] bf16 | VT[32][512] bf16 | P[4][16][512].
// 4 waves; each wave owns 16-row Q strips stepping by 64. Full-row softmax
// (ns <= 512 scores live in 128 VGPRs), P round-trips LDS for PV A-frags.
__global__ __launch_bounds__(256, 1) void k_attn(
    const u16* __restrict__ qb, const u16* __restrict__ kvb,
    const int* __restrict__ meta, u16* __restrict__ msgb) {
    extern __shared__ u16 sm[];
    u16* Kl = sm;                 // 32 KB
    u16* Vl = sm + 512 * 32;      // 32 KB (transposed: [d][m])
    u16* Pl = sm + 2 * 512 * 32;  // 64 KB
    int b = blockIdx.x, h = blockIdx.y;
    int ns = meta[b], nd = meta[64 + b];
    int soff = meta[128 + b], doff = meta[192 + b];
    int tid = threadIdx.x, w = tid >> 6, lane = tid & 63;
    int l15 = lane & 15, quad = lane >> 4;

    for (int i = tid; i < 16384; i += 256) ((u32*)sm)[i] = 0;  // zero K+VT
    __syncthreads();
    for (int m = tid; m < ns; m += 256) {
        const uint4* ksrc = (const uint4*)&kvb[(size_t)(soff + m) * 256 + h * 32];
#pragma unroll
        for (int q4 = 0; q4 < 4; q4++) *(uint4*)(&Kl[m * 32 + q4 * 8]) = ksrc[q4];
        uint4 vv[4];
        const uint4* vsrc = (const uint4*)&kvb[(size_t)(soff + m) * 256 + 128 + h * 32];
#pragma unroll
        for (int q4 = 0; q4 < 4; q4++) vv[q4] = vsrc[q4];
        const u16* pv = (const u16*)vv;
#pragma unroll
        for (int d = 0; d < 32; d++) Vl[d * 512 + m] = pv[d];
    }
    __syncthreads();

    u16* Pw = Pl + w * 16 * 512;
    const float qscale = 0.17677669529663687f;  // 1/sqrt(32)

    for (int s0 = w * 16; s0 < nd; s0 += 64) {
        int qr = s0 + l15; if (qr > nd - 1) qr = nd - 1;
        s8v aq = *(const s8v*)&qb[(size_t)(doff + qr) * 128 + h * 32 + quad * 8];

        f4v scv[32];
#pragma unroll
        for (int t = 0; t < 32; t++) {
            s8v bk_ = *(const s8v*)&Kl[(t * 16 + l15) * 32 + quad * 8];
            scv[t] = __builtin_amdgcn_mfma_f32_16x16x32_bf16(
                aq, bk_, (f4v){0.f, 0.f, 0.f, 0.f}, 0, 0, 0);
        }
        float mrow[4] = {-1e30f, -1e30f, -1e30f, -1e30f};
#pragma unroll
        for (int t = 0; t < 32; t++) {
            bool ok = (t * 16 + l15) < ns;
#pragma unroll
            for (int r = 0; r < 4; r++) {
                float v = ok ? scv[t][r] * qscale : -1e30f;
                scv[t][r] = v;
                mrow[r] = fmaxf(mrow[r], v);
            }
        }
#pragma unroll
        for (int r = 0; r < 4; r++) {
            float m_ = mrow[r];
#pragma unroll
            for (int x = 1; x < 16; x <<= 1) m_ = fmaxf(m_, __shfl_xor(m_, x, 16));
            mrow[r] = m_;
        }
        float lsum[4] = {0.f, 0.f, 0.f, 0.f};
#pragma unroll
        for (int t = 0; t < 32; t++)
#pragma unroll
            for (int r = 0; r < 4; r++) {
                float e = __expf(scv[t][r] - mrow[r]);
                scv[t][r] = e;
                lsum[r] += e;
            }
        float inv[4];
#pragma unroll
        for (int r = 0; r < 4; r++) {
            float s_ = lsum[r];
#pragma unroll
            for (int x = 1; x < 16; x <<= 1) s_ += __shfl_xor(s_, x, 16);
            inv[r] = 1.f / s_;
        }
#pragma unroll
        for (int t = 0; t < 32; t++) {
            int col = t * 16 + l15;
#pragma unroll
            for (int r = 0; r < 4; r++)
                Pw[(quad * 4 + r) * 512 + col] = f2bf(scv[t][r]);
        }
        f4v oa[2] = {{0.f, 0.f, 0.f, 0.f}, {0.f, 0.f, 0.f, 0.f}};
#pragma unroll
        for (int kc = 0; kc < 16; kc++) {
            s8v ap = *(const s8v*)&Pw[l15 * 512 + kc * 32 + quad * 8];
#pragma unroll
            for (int t = 0; t < 2; t++) {
                s8v bv_ = *(const s8v*)&Vl[(t * 16 + l15) * 512 + kc * 32 + quad * 8];
                oa[t] = __builtin_amdgcn_mfma_f32_16x16x32_bf16(ap, bv_, oa[t], 0, 0, 0);
            }
        }
#pragma unroll
        for (int t = 0; t < 2; t++)
#pragma unroll
            for (int r = 0; r < 4; r++) {
                int row = s0 + quad * 4 + r;
                if (row < nd)
                    msgb[(size_t)(doff + row) * 128 + h * 32 + t * 16 + l15] =
                        f2bf(oa[t][r] * inv[r]);
            }
    }
}

extern "C" void kernel_launch(void* const* d_in, const int* in_sizes, int n_in,
                              void* d_out, int out_size, void* d_ws, size_t ws_size,
                              hipStream_t stream) {
    const float* src_h = (const float*)d_in[0];
    const float* dst_h = (const float*)d_in[1];
    const int* snv = (const int*)d_in[2];
    const int* dnv = (const int*)d_in[3];
    const float* Wq = (const float*)d_in[4];  const float* bq = (const float*)d_in[5];
    const float* Wk = (const float*)d_in[6];  const float* bk = (const float*)d_in[7];
    const float* Wv = (const float*)d_in[8];  const float* bv = (const float*)d_in[9];
    const float* Wm = (const float*)d_in[10]; const float* bm = (const float*)d_in[11];
    const float* W1 = (const float*)d_in[12]; const float* b1 = (const float*)d_in[13];
    const float* g1 = (const float*)d_in[14]; const float* be1 = (const float*)d_in[15];
    const float* rm1 = (const float*)d_in[16]; const float* rv1 = (const float*)d_in[17];
    const float* W2 = (const float*)d_in[18]; const float* b2 = (const float*)d_in[19];
    const float* g2 = (const float*)d_in[20]; const float* be2 = (const float*)d_in[21];
    const float* rm2 = (const float*)d_in[22]; const float* rv2 = (const float*)d_in[23];

    int ntot = out_size / HDIM;  // 24576
    int mt = ntot / 128;         // 192 M-tiles

    // ws layout (bytes), ~31 MB total:
    char* ws = (char*)d_ws;
    int* meta = (int*)ws;                       // @0
    float* bqp = (float*)(ws + 4096);           // 128 f32
    float* bkvp = (float*)(ws + 4608);          // 256
    float* bmp = (float*)(ws + 5632);           // 128
    float* sc1 = (float*)(ws + 6144);           // 256
    float* sh1 = (float*)(ws + 7168);           // 256
    float* sc2 = (float*)(ws + 8192);           // 256
    float* sh2 = (float*)(ws + 9216);           // 256
    u16* pWq = (u16*)(ws + 16384);              // 32768 elems
    u16* pWkv = (u16*)(ws + 81920);             // 65536
    u16* pWm = (u16*)(ws + 212992);             // 16384
    u16* pW1 = (u16*)(ws + 245760);             // 98304
    u16* pW2 = (u16*)(ws + 442368);             // 65536
    u16* srcb = (u16*)(ws + 1048576);           // ntot*256 bf16 (12.6 MB)
    u16* x1b = srcb;                            // reuse after G_kv consumed
    u16* xcat = (u16*)(ws + 13631488);          // ntot*384 bf16 (18.9 MB)

    // d_out doubles as q/kv/msg scratch (exactly out_size*4 bytes):
    u16* qb = (u16*)d_out;                      // ntot*128
    u16* kvb = qb + (size_t)ntot * 128;         // ntot*256
    u16* msgb = kvb + (size_t)ntot * 256;       // ntot*128

    hipFuncSetAttribute((const void*)k_attn,
                        hipFuncAttributeMaxDynamicSharedMemorySize, 131072);

    k_offsets<<<dim3(1), dim3(64), 0, stream>>>(snv, dnv, meta);
    k_prep<<<dim3(1092), dim3(256), 0, stream>>>(
        Wq, bq, Wk, bk, Wv, bv, Wm, bm, W1, b1, g1, be1, rm1, rv1,
        W2, b2, g2, be2, rm2, rv2,
        pWq, pWkv, pWm, pW1, pW2, bqp, bkvp, bmp, sc1, sh1, sc2, sh2);
    k_convert<<<dim3(ntot * 64 / 256, 2), dim3(256), 0, stream>>>(
        src_h, dst_h, srcb, xcat, ntot);
    // q = dst (xcat cols 0..255) @ Wq'^T + bq'
    k_gemm<<<dim3(mt, 1), dim3(256), 0, stream>>>(
        xcat, 384, pWq, 256, nullptr, bqp, nullptr, qb, 128, 0, 0);
    // k|v = src @ Wkv'^T + bkv'
    k_gemm<<<dim3(mt, 2), dim3(256), 0, stream>>>(
        srcb, 256, pWkv, 256, nullptr, bkvp, nullptr, kvb, 256, 0, 0);
    k_attn<<<dim3(B_SEG, NHEADS), dim3(256), 131072, stream>>>(qb, kvb, meta, msgb);
    // hm = msg @ Wm'^T + bm -> xcat cols 256..383
    k_gemm<<<dim3(mt, 1), dim3(256), 0, stream>>>(
        msgb, 128, pWm, 128, nullptr, bmp, nullptr, xcat, 384, 256, 0);
    // x1 = relu(bn1(xcat @ W1^T))
    k_gemm<<<dim3(mt, 2), dim3(256), 0, stream>>>(
        xcat, 384, pW1, 384, sc1, sh1, nullptr, x1b, 256, 0, 1);
    // out = dst_h + bn2(x1 @ W2^T)   (f32, overwrites scratch in d_out)
    k_gemm<<<dim3(mt, 2), dim3(256), 0, stream>>>(
        x1b, 256, pW2, 256, sc2, sh2, dst_h, d_out, 256, 0, 2);
}